// Round 6
// baseline (2815.941 us; speedup 1.0000x reference)
//
#include <hip/hip_runtime.h>
#include <math.h>

#define NPTS 4096
#define NBATCH 4
#define BLOCK 256
#define RPW 4            // rows per wave (coords in SGPRs)

static constexpr float KSCALE     = 1.4426950408889634f / 1e-4f;   // log2(e)/eps
static constexpr float INVK2      = 1.0f / (KSCALE * KSCALE);
static constexpr float EPSLN2     = 1e-4f * 0.6931471805599453f;   // eps*ln(2)
static constexpr float NEGEPSLOGW = 8.31776616671934e-4f;          // -eps * (-log(4096))
static constexpr float THR        = 18.0f;   // skip chunks < m-18 (mass loss <= 4096*2^-18)

__device__ __forceinline__ float fexp2(float x){
#if __has_builtin(__builtin_amdgcn_exp2f)
  return __builtin_amdgcn_exp2f(x);
#else
  return exp2f(x);
#endif
}
__device__ __forceinline__ float flog2(float x){
#if __has_builtin(__builtin_amdgcn_logf)
  return __builtin_amdgcn_logf(x);
#else
  return log2f(x);
#endif
}
__device__ __forceinline__ float frl(float x){
  return __int_as_float(__builtin_amdgcn_readfirstlane(__float_as_int(x)));
}

// Two-phase softmin. One launch = two independent problems (1024 blocks each).
// Block = 256 thr = 4 independent waves; wave owns 4 rows (coords in SGPRs).
// Columns lane-distinct (lane l owns cols l+64j), 4 coalesced float4 loads per
// 256-col group, fully unrolled.
// Phase A: dots + max trees only -> cmax[4 chunks][4 rows]; shfl-max -> exact m.
// Phase B: re-dot + exp2 ONLY for 1024-col chunks with __any(cmax > m-THR).
// No trans ops in phase A; skip is sound (m is the exact global max).
__global__ __launch_bounds__(BLOCK, 8) void softmin_kernel(
    const float* __restrict__ rowA, int rsA, const float4* __restrict__ pkInA,
    float4* __restrict__ pkOutA, const float* __restrict__ hOldA,
    float* __restrict__ outA, int modeA,
    const float* __restrict__ rowB, int rsB, const float4* __restrict__ pkInB,
    float4* __restrict__ pkOutB, const float* __restrict__ hOldB,
    float* __restrict__ outB, int modeB)
{
  int bid = blockIdx.x;
  const float* rowp; const float4* pkin; float4* pkout; const float* hold;
  float* outp; int rs, mode;
  if (bid < 1024) { rowp=rowA; pkin=pkInA; pkout=pkOutA; hold=hOldA; outp=outA; rs=rsA; mode=modeA; }
  else            { rowp=rowB; pkin=pkInB; pkout=pkOutB; hold=hOldB; outp=outB; rs=rsB; mode=modeB; }
  int lb = bid & 1023;
  int b  = lb >> 8;          // batch (256 blocks per batch)
  int rb = lb & 255;         // row-block (16 rows per block)

  int tid = threadIdx.x;
  int lane = tid & 63;
  int wu = __builtin_amdgcn_readfirstlane(tid >> 6);
  int r0 = rb*16 + wu*RPW;
  int ridx0 = b*NPTS + r0;

  // wave-uniform row coords -> SGPRs
  float sx[RPW], sy[RPW], sz[RPW];
  #pragma unroll
  for (int i = 0; i < RPW; ++i) {
    const float* p = rowp + (size_t)(ridx0 + i) * rs;
    sx[i] = frl(p[0]*KSCALE); sy[i] = frl(p[1]*KSCALE); sz[i] = frl(p[2]*KSCALE);
  }

  const float4* pkL = pkin + b*NPTS + lane;

  // ---- phase A: exact per-row global max (no trans ops) ----
  float cmax[4][RPW];
  #pragma unroll
  for (int c = 0; c < 4; ++c)
    #pragma unroll
    for (int r = 0; r < RPW; ++r) cmax[c][r] = -INFINITY;

  #pragma unroll
  for (int c = 0; c < 4; ++c) {
    #pragma unroll
    for (int g = 0; g < 4; ++g) {
      int base = c*1024 + g*256;
      float4 q0 = pkL[base], q1 = pkL[base+64], q2 = pkL[base+128], q3 = pkL[base+192];
      #pragma unroll
      for (int r = 0; r < RPW; ++r) {
        float t0 = fmaf(sx[r],q0.x,fmaf(sy[r],q0.y,fmaf(sz[r],q0.z,q0.w)));
        float t1 = fmaf(sx[r],q1.x,fmaf(sy[r],q1.y,fmaf(sz[r],q1.z,q1.w)));
        float t2 = fmaf(sx[r],q2.x,fmaf(sy[r],q2.y,fmaf(sz[r],q2.z,q2.w)));
        float t3 = fmaf(sx[r],q3.x,fmaf(sy[r],q3.y,fmaf(sz[r],q3.z,q3.w)));
        cmax[c][r] = fmaxf(fmaxf(t0,t1), fmaxf(t2, fmaxf(t3, cmax[c][r])));
      }
    }
  }

  float mu[RPW], thr[RPW];
  #pragma unroll
  for (int r = 0; r < RPW; ++r) {
    float mm = fmaxf(fmaxf(cmax[0][r],cmax[1][r]), fmaxf(cmax[2][r],cmax[3][r]));
    #pragma unroll
    for (int off = 32; off; off >>= 1) mm = fmaxf(mm, __shfl_xor(mm, off, 64));
    mu[r]  = frl(mm);
    thr[r] = frl(mm - THR);
  }

  // ---- phase B: exp2 over active chunks only ----
  float S[RPW];
  #pragma unroll
  for (int r = 0; r < RPW; ++r) S[r] = 0.f;

  #pragma unroll
  for (int c = 0; c < 4; ++c) {
    bool a0 = __any(cmax[c][0] > thr[0]);
    bool a1 = __any(cmax[c][1] > thr[1]);
    bool a2 = __any(cmax[c][2] > thr[2]);
    bool a3 = __any(cmax[c][3] > thr[3]);
    if (a0 | a1 | a2 | a3) {
      #pragma unroll
      for (int g = 0; g < 4; ++g) {
        int base = c*1024 + g*256;
        float4 q0 = pkL[base], q1 = pkL[base+64], q2 = pkL[base+128], q3 = pkL[base+192];
        if (a0) {
          float u0 = fexp2(fmaf(sx[0],q0.x,fmaf(sy[0],q0.y,fmaf(sz[0],q0.z,q0.w))) - mu[0]);
          float u1 = fexp2(fmaf(sx[0],q1.x,fmaf(sy[0],q1.y,fmaf(sz[0],q1.z,q1.w))) - mu[0]);
          float u2 = fexp2(fmaf(sx[0],q2.x,fmaf(sy[0],q2.y,fmaf(sz[0],q2.z,q2.w))) - mu[0]);
          float u3 = fexp2(fmaf(sx[0],q3.x,fmaf(sy[0],q3.y,fmaf(sz[0],q3.z,q3.w))) - mu[0]);
          S[0] += (u0+u1) + (u2+u3);
        }
        if (a1) {
          float u0 = fexp2(fmaf(sx[1],q0.x,fmaf(sy[1],q0.y,fmaf(sz[1],q0.z,q0.w))) - mu[1]);
          float u1 = fexp2(fmaf(sx[1],q1.x,fmaf(sy[1],q1.y,fmaf(sz[1],q1.z,q1.w))) - mu[1]);
          float u2 = fexp2(fmaf(sx[1],q2.x,fmaf(sy[1],q2.y,fmaf(sz[1],q2.z,q2.w))) - mu[1]);
          float u3 = fexp2(fmaf(sx[1],q3.x,fmaf(sy[1],q3.y,fmaf(sz[1],q3.z,q3.w))) - mu[1]);
          S[1] += (u0+u1) + (u2+u3);
        }
        if (a2) {
          float u0 = fexp2(fmaf(sx[2],q0.x,fmaf(sy[2],q0.y,fmaf(sz[2],q0.z,q0.w))) - mu[2]);
          float u1 = fexp2(fmaf(sx[2],q1.x,fmaf(sy[2],q1.y,fmaf(sz[2],q1.z,q1.w))) - mu[2]);
          float u2 = fexp2(fmaf(sx[2],q2.x,fmaf(sy[2],q2.y,fmaf(sz[2],q2.z,q2.w))) - mu[2]);
          float u3 = fexp2(fmaf(sx[2],q3.x,fmaf(sy[2],q3.y,fmaf(sz[2],q3.z,q3.w))) - mu[2]);
          S[2] += (u0+u1) + (u2+u3);
        }
        if (a3) {
          float u0 = fexp2(fmaf(sx[3],q0.x,fmaf(sy[3],q0.y,fmaf(sz[3],q0.z,q0.w))) - mu[3]);
          float u1 = fexp2(fmaf(sx[3],q1.x,fmaf(sy[3],q1.y,fmaf(sz[3],q1.z,q1.w))) - mu[3]);
          float u2 = fexp2(fmaf(sx[3],q2.x,fmaf(sy[3],q2.y,fmaf(sz[3],q2.z,q2.w))) - mu[3]);
          float u3 = fexp2(fmaf(sx[3],q3.x,fmaf(sy[3],q3.y,fmaf(sz[3],q3.z,q3.w))) - mu[3]);
          S[3] += (u0+u1) + (u2+u3);
        }
      }
    }
  }

  // ---- merge + write ----
  #pragma unroll
  for (int r = 0; r < RPW; ++r) {
    float s = S[r];
    #pragma unroll
    for (int off = 32; off; off >>= 1) s += __shfl_xor(s, off, 64);
    float ch = 0.5f*(sx[r]*sx[r] + sy[r]*sy[r] + sz[r]*sz[r]) * INVK2;
    float res = fmaf(-EPSLN2, mu[r] + flog2(s), ch + NEGEPSLOGW);
    if (lane == r) {
      if (mode) res = 0.5f*(hold[ridx0 + r] + res);
      outp[ridx0 + r] = res;
      ((float*)(pkout + (ridx0 + r)))[3] = (res - ch) * KSCALE;
    }
  }
}

// Build the 6 packed column arrays once per launch. .w gets the h=0 initial Atilde.
__global__ void pack_init(const float* __restrict__ x, const float* __restrict__ y,
                          float4* pkfab, float4* pkgab,
                          float4* pkfaa0, float4* pkfaa1,
                          float4* pkgbb0, float4* pkgbb1)
{
  int i = blockIdx.x*256 + threadIdx.x;        // 0..16383 == b*4096+m
  const float* xp = x + (size_t)i*3;
  float xx = xp[0], xy = xp[1], xz = xp[2];
  float4 vx; vx.x=xx; vx.y=xy; vx.z=xz;
  vx.w = -0.5f*(xx*xx + xy*xy + xz*xz)*KSCALE;
  const float* yp = y + (size_t)i*4;
  float yx = yp[0], yy = yp[1], yz = yp[2];
  float4 vy; vy.x=yx; vy.y=yy; vy.z=yz;
  vy.w = -0.5f*(yx*yx + yy*yy + yz*yz)*KSCALE;
  pkgab[i]  = vx; pkfaa0[i] = vx; pkfaa1[i] = vx;
  pkfab[i]  = vy; pkgbb0[i] = vy; pkgbb1[i] = vy;
}

__global__ void reduce_kernel(const float* __restrict__ fab, const float* __restrict__ faa,
                              const float* __restrict__ gab, const float* __restrict__ gbb,
                              float* __restrict__ out)
{
  int b = blockIdx.x;
  int tid = threadIdx.x;
  float s = 0.f;
  for (int i = tid; i < NPTS; i += 256) {
    int idx = b*NPTS + i;
    s += (fab[idx] - faa[idx]) + (gab[idx] - gbb[idx]);
  }
  for (int off = 32; off > 0; off >>= 1) s += __shfl_down(s, off, 64);
  __shared__ float red[4];
  if ((tid & 63) == 0) red[tid >> 6] = s;
  __syncthreads();
  if (tid == 0) out[b] = (red[0]+red[1]+red[2]+red[3]) * (1.0f/NPTS);
}

extern "C" void kernel_launch(void* const* d_in, const int* in_sizes, int n_in,
                              void* d_out, int out_size, void* d_ws, size_t ws_size,
                              hipStream_t stream)
{
  const float* x = (const float*)d_in[0];   // (4,4096,3)
  const float* y = (const float*)d_in[1];   // (4,4096,4), first 3 comps used
  float* ws = (float*)d_ws;
  const size_t P = (size_t)NBATCH * NPTS;   // 16384

  float* f_ab    = ws + 0*P;
  float* g_ab    = ws + 1*P;
  float* faaR[2] = { ws + 2*P, ws + 4*P };
  float* gbbR[2] = { ws + 3*P, ws + 5*P };
  float4* pk4    = (float4*)(ws + 6*P);
  float4* PKfab    = pk4 + 0*P;             // cols = y, .w = Atilde(g_ab)
  float4* PKgab    = pk4 + 1*P;             // cols = x, .w = Atilde(f_ab)
  float4* PKfaa[2] = { pk4 + 2*P, pk4 + 3*P };
  float4* PKgbb[2] = { pk4 + 4*P, pk4 + 5*P };

  // zero h_old for the first averaged symmetric step (faaR[0], gbbR[0] contiguous)
  hipMemsetAsync(ws + 2*P, 0, 2*P*sizeof(float), stream);
  pack_init<<<dim3(P/256), dim3(256), 0, stream>>>(x, y, PKfab, PKgab,
                                                   PKfaa[0], PKfaa[1], PKgbb[0], PKgbb[1]);

  for (int i = 0; i < 21; ++i) {
    int cur = i & 1, nxt = cur ^ 1;
    int modeS = (i < 20) ? 1 : 0;    // averaged symmetric update except final softmin
    // phase 1: f_ab = softmin over y-cols (Atilde from g_ab)  ||  f_aa step
    softmin_kernel<<<2048, BLOCK, 0, stream>>>(
        x, 3, PKfab, PKgab, f_ab, f_ab, 0,
        x, 3, PKfaa[cur], PKfaa[nxt], faaR[cur], faaR[nxt], modeS);
    // phase 2: g_ab = softmin over x-cols (Atilde from f_ab)  ||  g_bb step
    softmin_kernel<<<2048, BLOCK, 0, stream>>>(
        y, 4, PKgab, PKfab, g_ab, g_ab, 0,
        y, 4, PKgbb[cur], PKgbb[nxt], gbbR[cur], gbbR[nxt], modeS);
  }
  // i=20 wrote faaR[1]/gbbR[1]
  reduce_kernel<<<dim3(4), dim3(256), 0, stream>>>(f_ab, faaR[1], g_ab, gbbR[1], (float*)d_out);
}

// Round 7
// 1444.721 us; speedup vs baseline: 1.9491x; 1.9491x over previous
//
#include <hip/hip_runtime.h>
#include <math.h>

#define NPTS 4096
#define NBATCH 4
#define BLOCK 256
#define RPW 4            // rows per wave (coords in SGPRs)

static constexpr float KSCALE     = 1.4426950408889634f / 1e-4f;   // log2(e)/eps
static constexpr float INVK2      = 1.0f / (KSCALE * KSCALE);
static constexpr float EPSLN2     = 1e-4f * 0.6931471805599453f;   // eps*ln(2)
static constexpr float NEGEPSLOGW = 8.31776616671934e-4f;          // -eps * (-log(4096))
static constexpr float THR        = 20.0f;   // drop groups < mu-20: rel mass <= 4096*2^-20

__device__ __forceinline__ float fexp2(float x){
#if __has_builtin(__builtin_amdgcn_exp2f)
  return __builtin_amdgcn_exp2f(x);
#else
  return exp2f(x);
#endif
}
__device__ __forceinline__ float flog2(float x){
#if __has_builtin(__builtin_amdgcn_logf)
  return __builtin_amdgcn_logf(x);
#else
  return log2f(x);
#endif
}
__device__ __forceinline__ float frl(float x){
  return __int_as_float(__builtin_amdgcn_readfirstlane(__float_as_int(x)));
}

// Two-pass softmin with ZERO stored per-chunk state (R5 post-mortem: any
// phase-A array living into phase B spills). One launch = two problems
// (1024 blocks each). Block = 256 thr = 4 independent waves; wave owns 4
// rows (coords readfirstlane'd to SGPRs, one SGPR src per v_fma).
// Columns lane-distinct: lane l owns cols l+64j, 4 coalesced float4 loads
// per 256-col group, reused across 4 rows.
// Pass A: dots + max3 fold -> running M[4] only. shfl-max -> exact mu.
// Pass B: re-dot, group max, vote vs (mu-THR); exp2 block only for active
// groups (~3-13%). mu is final => no rescale path at all.
__global__ __launch_bounds__(BLOCK, 4) void softmin_kernel(
    const float* __restrict__ rowA, int rsA, const float4* __restrict__ pkInA,
    float4* __restrict__ pkOutA, const float* __restrict__ hOldA,
    float* __restrict__ outA, int modeA,
    const float* __restrict__ rowB, int rsB, const float4* __restrict__ pkInB,
    float4* __restrict__ pkOutB, const float* __restrict__ hOldB,
    float* __restrict__ outB, int modeB)
{
  int bid = blockIdx.x;
  const float* rowp; const float4* pkin; float4* pkout; const float* hold;
  float* outp; int rs, mode;
  if (bid < 1024) { rowp=rowA; pkin=pkInA; pkout=pkOutA; hold=hOldA; outp=outA; rs=rsA; mode=modeA; }
  else            { rowp=rowB; pkin=pkInB; pkout=pkOutB; hold=hOldB; outp=outB; rs=rsB; mode=modeB; }
  int lb = bid & 1023;
  int b  = lb >> 8;          // batch (256 blocks per batch)
  int rb = lb & 255;         // row-block (16 rows per block)

  int tid = threadIdx.x;
  int lane = tid & 63;
  int wu = __builtin_amdgcn_readfirstlane(tid >> 6);
  int r0 = rb*16 + wu*RPW;
  int ridx0 = b*NPTS + r0;

  // wave-uniform row coords -> SGPRs
  float sx[RPW], sy[RPW], sz[RPW];
  #pragma unroll
  for (int i = 0; i < RPW; ++i) {
    const float* p = rowp + (size_t)(ridx0 + i) * rs;
    sx[i] = frl(p[0]*KSCALE); sy[i] = frl(p[1]*KSCALE); sz[i] = frl(p[2]*KSCALE);
  }

  // ---- pass A: exact per-row global max (no trans ops, no history) ----
  float M[RPW];
  #pragma unroll
  for (int r = 0; r < RPW; ++r) M[r] = -INFINITY;

  const float4* pk = pkin + b*NPTS + lane;
  for (int g = 0; g < 16; ++g) {
    float4 q0 = pk[0], q1 = pk[64], q2 = pk[128], q3 = pk[192];
    pk += 256;
    #pragma unroll
    for (int r = 0; r < RPW; ++r) {
      float t0 = fmaf(sx[r],q0.x,fmaf(sy[r],q0.y,fmaf(sz[r],q0.z,q0.w)));
      float t1 = fmaf(sx[r],q1.x,fmaf(sy[r],q1.y,fmaf(sz[r],q1.z,q1.w)));
      float t2 = fmaf(sx[r],q2.x,fmaf(sy[r],q2.y,fmaf(sz[r],q2.z,q2.w)));
      float t3 = fmaf(sx[r],q3.x,fmaf(sy[r],q3.y,fmaf(sz[r],q3.z,q3.w)));
      float u  = fmaxf(fmaxf(t0,t1),t2);        // v_max3
      M[r] = fmaxf(fmaxf(u,t3),M[r]);           // v_max3
    }
  }

  float mu[RPW], thr[RPW];
  #pragma unroll
  for (int r = 0; r < RPW; ++r) {
    float mm = M[r];
    #pragma unroll
    for (int off = 32; off; off >>= 1) mm = fmaxf(mm, __shfl_xor(mm, off, 64));
    mu[r]  = mm;
    thr[r] = mm - THR;
  }

  // ---- pass B: sum exp2 only over groups that can contribute ----
  float S[RPW];
  #pragma unroll
  for (int r = 0; r < RPW; ++r) S[r] = 0.f;

  pk = pkin + b*NPTS + lane;
  for (int g = 0; g < 16; ++g) {
    float4 q0 = pk[0], q1 = pk[64], q2 = pk[128], q3 = pk[192];
    pk += 256;
    #pragma unroll
    for (int r = 0; r < RPW; ++r) {
      float t0 = fmaf(sx[r],q0.x,fmaf(sy[r],q0.y,fmaf(sz[r],q0.z,q0.w)));
      float t1 = fmaf(sx[r],q1.x,fmaf(sy[r],q1.y,fmaf(sz[r],q1.z,q1.w)));
      float t2 = fmaf(sx[r],q2.x,fmaf(sy[r],q2.y,fmaf(sz[r],q2.z,q2.w)));
      float t3 = fmaf(sx[r],q3.x,fmaf(sy[r],q3.y,fmaf(sz[r],q3.z,q3.w)));
      float u  = fmaxf(fmaxf(t0,t1),t2);
      float v  = fmaxf(u,t3);
      if (__any(v > thr[r])) {
        float e0 = fexp2(t0-mu[r]) + fexp2(t1-mu[r]);
        float e1 = fexp2(t2-mu[r]) + fexp2(t3-mu[r]);
        S[r] += e0 + e1;
      }
    }
  }

  // ---- merge + write ----
  #pragma unroll
  for (int r = 0; r < RPW; ++r) {
    float s = S[r];
    #pragma unroll
    for (int off = 32; off; off >>= 1) s += __shfl_xor(s, off, 64);
    float ch = 0.5f*(sx[r]*sx[r] + sy[r]*sy[r] + sz[r]*sz[r]) * INVK2;
    float res = fmaf(-EPSLN2, mu[r] + flog2(s), ch + NEGEPSLOGW);
    if (lane == r) {
      if (mode) res = 0.5f*(hold[ridx0 + r] + res);
      outp[ridx0 + r] = res;
      ((float*)(pkout + (ridx0 + r)))[3] = (res - ch) * KSCALE;
    }
  }
}

// Build the 6 packed column arrays once per launch. .w gets the h=0 initial Atilde.
__global__ void pack_init(const float* __restrict__ x, const float* __restrict__ y,
                          float4* pkfab, float4* pkgab,
                          float4* pkfaa0, float4* pkfaa1,
                          float4* pkgbb0, float4* pkgbb1)
{
  int i = blockIdx.x*256 + threadIdx.x;        // 0..16383 == b*4096+m
  const float* xp = x + (size_t)i*3;
  float xx = xp[0], xy = xp[1], xz = xp[2];
  float4 vx; vx.x=xx; vx.y=xy; vx.z=xz;
  vx.w = -0.5f*(xx*xx + xy*xy + xz*xz)*KSCALE;
  const float* yp = y + (size_t)i*4;
  float yx = yp[0], yy = yp[1], yz = yp[2];
  float4 vy; vy.x=yx; vy.y=yy; vy.z=yz;
  vy.w = -0.5f*(yx*yx + yy*yy + yz*yz)*KSCALE;
  pkgab[i]  = vx; pkfaa0[i] = vx; pkfaa1[i] = vx;
  pkfab[i]  = vy; pkgbb0[i] = vy; pkgbb1[i] = vy;
}

__global__ void reduce_kernel(const float* __restrict__ fab, const float* __restrict__ faa,
                              const float* __restrict__ gab, const float* __restrict__ gbb,
                              float* __restrict__ out)
{
  int b = blockIdx.x;
  int tid = threadIdx.x;
  float s = 0.f;
  for (int i = tid; i < NPTS; i += 256) {
    int idx = b*NPTS + i;
    s += (fab[idx] - faa[idx]) + (gab[idx] - gbb[idx]);
  }
  for (int off = 32; off > 0; off >>= 1) s += __shfl_down(s, off, 64);
  __shared__ float red[4];
  if ((tid & 63) == 0) red[tid >> 6] = s;
  __syncthreads();
  if (tid == 0) out[b] = (red[0]+red[1]+red[2]+red[3]) * (1.0f/NPTS);
}

extern "C" void kernel_launch(void* const* d_in, const int* in_sizes, int n_in,
                              void* d_out, int out_size, void* d_ws, size_t ws_size,
                              hipStream_t stream)
{
  const float* x = (const float*)d_in[0];   // (4,4096,3)
  const float* y = (const float*)d_in[1];   // (4,4096,4), first 3 comps used
  float* ws = (float*)d_ws;
  const size_t P = (size_t)NBATCH * NPTS;   // 16384

  float* f_ab    = ws + 0*P;
  float* g_ab    = ws + 1*P;
  float* faaR[2] = { ws + 2*P, ws + 4*P };
  float* gbbR[2] = { ws + 3*P, ws + 5*P };
  float4* pk4    = (float4*)(ws + 6*P);
  float4* PKfab    = pk4 + 0*P;             // cols = y, .w = Atilde(g_ab)
  float4* PKgab    = pk4 + 1*P;             // cols = x, .w = Atilde(f_ab)
  float4* PKfaa[2] = { pk4 + 2*P, pk4 + 3*P };
  float4* PKgbb[2] = { pk4 + 4*P, pk4 + 5*P };

  // zero h_old for the first averaged symmetric step (faaR[0], gbbR[0] contiguous)
  hipMemsetAsync(ws + 2*P, 0, 2*P*sizeof(float), stream);
  pack_init<<<dim3(P/256), dim3(256), 0, stream>>>(x, y, PKfab, PKgab,
                                                   PKfaa[0], PKfaa[1], PKgbb[0], PKgbb[1]);

  for (int i = 0; i < 21; ++i) {
    int cur = i & 1, nxt = cur ^ 1;
    int modeS = (i < 20) ? 1 : 0;    // averaged symmetric update except final softmin
    // phase 1: f_ab = softmin over y-cols (Atilde from g_ab)  ||  f_aa step
    softmin_kernel<<<2048, BLOCK, 0, stream>>>(
        x, 3, PKfab, PKgab, f_ab, f_ab, 0,
        x, 3, PKfaa[cur], PKfaa[nxt], faaR[cur], faaR[nxt], modeS);
    // phase 2: g_ab = softmin over x-cols (Atilde from f_ab)  ||  g_bb step
    softmin_kernel<<<2048, BLOCK, 0, stream>>>(
        y, 4, PKgab, PKfab, g_ab, g_ab, 0,
        y, 4, PKgbb[cur], PKgbb[nxt], gbbR[cur], gbbR[nxt], modeS);
  }
  // i=20 wrote faaR[1]/gbbR[1]
  reduce_kernel<<<dim3(4), dim3(256), 0, stream>>>(f_ab, faaR[1], g_ab, gbbR[1], (float*)d_out);
}

// Round 8
// 1247.648 us; speedup vs baseline: 2.2570x; 1.1580x over previous
//
#include <hip/hip_runtime.h>
#include <math.h>

#define NPTS 4096
#define NBATCH 4
#define BLOCK 256
#define RPW 8            // rows per wave (coords in SGPRs; R4's proven-clean shape)

static constexpr float KSCALE     = 1.4426950408889634f / 1e-4f;   // log2(e)/eps
static constexpr float INVK2      = 1.0f / (KSCALE * KSCALE);
static constexpr float EPSLN2     = 1e-4f * 0.6931471805599453f;   // eps*ln(2)
static constexpr float NEGEPSLOGW = 8.31776616671934e-4f;          // -eps * (-log(4096))
static constexpr float THR        = 20.0f;   // drop groups < mu-20: rel mass <= 4096*2^-20

__device__ __forceinline__ float fexp2(float x){
#if __has_builtin(__builtin_amdgcn_exp2f)
  return __builtin_amdgcn_exp2f(x);
#else
  return exp2f(x);
#endif
}
__device__ __forceinline__ float flog2(float x){
#if __has_builtin(__builtin_amdgcn_logf)
  return __builtin_amdgcn_logf(x);
#else
  return log2f(x);
#endif
}
__device__ __forceinline__ float frl(float x){
  return __int_as_float(__builtin_amdgcn_readfirstlane(__float_as_int(x)));
}

// Two-pass softmin, RPW=8 (VMEM reuse: one 16B column load feeds 8 rows).
// One launch = two problems (512 blocks each). Block = 256 thr = 4 waves.
// Wave owns 8 rows (coords in SGPRs via readfirstlane). Columns lane-
// distinct (lane l owns cols l+64j), 4 coalesced float4 loads per 256-col
// group, reused across 8 rows. No per-chunk state (R5 lesson).
// Pass A: dots + max3 fold -> M[8]; shfl-max -> exact mu[8].
// Pass B: re-dot, group max, vote (v-mu[r]) > -THR; exp2 only when active.
__global__ __launch_bounds__(BLOCK, 4) void softmin_kernel(
    const float* __restrict__ rowA, int rsA, const float4* __restrict__ pkInA,
    float4* __restrict__ pkOutA, const float* __restrict__ hOldA,
    float* __restrict__ outA, int modeA,
    const float* __restrict__ rowB, int rsB, const float4* __restrict__ pkInB,
    float4* __restrict__ pkOutB, const float* __restrict__ hOldB,
    float* __restrict__ outB, int modeB)
{
  int bid = blockIdx.x;
  const float* rowp; const float4* pkin; float4* pkout; const float* hold;
  float* outp; int rs, mode;
  if (bid < 512) { rowp=rowA; pkin=pkInA; pkout=pkOutA; hold=hOldA; outp=outA; rs=rsA; mode=modeA; }
  else           { rowp=rowB; pkin=pkInB; pkout=pkOutB; hold=hOldB; outp=outB; rs=rsB; mode=modeB; }
  int lb = bid & 511;
  int b  = lb >> 7;          // batch (128 blocks per batch)
  int rb = lb & 127;         // row-block (32 rows per block)

  int tid = threadIdx.x;
  int lane = tid & 63;
  int wu = __builtin_amdgcn_readfirstlane(tid >> 6);
  int r0 = rb*32 + wu*RPW;
  int ridx0 = b*NPTS + r0;

  // wave-uniform row coords -> SGPRs
  float sx[RPW], sy[RPW], sz[RPW];
  #pragma unroll
  for (int i = 0; i < RPW; ++i) {
    const float* p = rowp + (size_t)(ridx0 + i) * rs;
    sx[i] = frl(p[0]*KSCALE); sy[i] = frl(p[1]*KSCALE); sz[i] = frl(p[2]*KSCALE);
  }

  // ---- pass A: exact per-row global max (no trans ops, no history) ----
  float M[RPW];
  #pragma unroll
  for (int r = 0; r < RPW; ++r) M[r] = -INFINITY;

  const float4* pk = pkin + b*NPTS + lane;
  for (int g = 0; g < 16; ++g) {
    float4 q0 = pk[0], q1 = pk[64], q2 = pk[128], q3 = pk[192];
    pk += 256;
    #pragma unroll
    for (int r = 0; r < RPW; ++r) {
      float t0 = fmaf(sx[r],q0.x,fmaf(sy[r],q0.y,fmaf(sz[r],q0.z,q0.w)));
      float t1 = fmaf(sx[r],q1.x,fmaf(sy[r],q1.y,fmaf(sz[r],q1.z,q1.w)));
      float t2 = fmaf(sx[r],q2.x,fmaf(sy[r],q2.y,fmaf(sz[r],q2.z,q2.w)));
      float t3 = fmaf(sx[r],q3.x,fmaf(sy[r],q3.y,fmaf(sz[r],q3.z,q3.w)));
      float u  = fmaxf(fmaxf(t0,t1),t2);        // v_max3
      M[r] = fmaxf(fmaxf(u,t3),M[r]);           // v_max3
    }
  }

  // exact global max per row (kept in VGPRs; mu == M after this)
  #pragma unroll
  for (int r = 0; r < RPW; ++r) {
    float mm = M[r];
    #pragma unroll
    for (int off = 32; off; off >>= 1) mm = fmaxf(mm, __shfl_xor(mm, off, 64));
    M[r] = mm;
  }

  // ---- pass B: sum exp2 only over groups that can contribute ----
  float S[RPW];
  #pragma unroll
  for (int r = 0; r < RPW; ++r) S[r] = 0.f;

  pk = pkin + b*NPTS + lane;
  for (int g = 0; g < 16; ++g) {
    float4 q0 = pk[0], q1 = pk[64], q2 = pk[128], q3 = pk[192];
    pk += 256;
    #pragma unroll
    for (int r = 0; r < RPW; ++r) {
      float t0 = fmaf(sx[r],q0.x,fmaf(sy[r],q0.y,fmaf(sz[r],q0.z,q0.w)));
      float t1 = fmaf(sx[r],q1.x,fmaf(sy[r],q1.y,fmaf(sz[r],q1.z,q1.w)));
      float t2 = fmaf(sx[r],q2.x,fmaf(sy[r],q2.y,fmaf(sz[r],q2.z,q2.w)));
      float t3 = fmaf(sx[r],q3.x,fmaf(sy[r],q3.y,fmaf(sz[r],q3.z,q3.w)));
      float u  = fmaxf(fmaxf(t0,t1),t2);
      float v  = fmaxf(u,t3) - M[r];            // <= 0; active iff > -THR
      if (__any(v > -THR)) {
        float e0 = fexp2(t0-M[r]) + fexp2(t1-M[r]);
        float e1 = fexp2(t2-M[r]) + fexp2(t3-M[r]);
        S[r] += e0 + e1;
      }
    }
  }

  // ---- merge + write ----
  #pragma unroll
  for (int r = 0; r < RPW; ++r) {
    float s = S[r];
    #pragma unroll
    for (int off = 32; off; off >>= 1) s += __shfl_xor(s, off, 64);
    float ch = 0.5f*(sx[r]*sx[r] + sy[r]*sy[r] + sz[r]*sz[r]) * INVK2;
    float res = fmaf(-EPSLN2, M[r] + flog2(s), ch + NEGEPSLOGW);
    if (lane == r) {
      if (mode) res = 0.5f*(hold[ridx0 + r] + res);
      outp[ridx0 + r] = res;
      ((float*)(pkout + (ridx0 + r)))[3] = (res - ch) * KSCALE;
    }
  }
}

// Build the 6 packed column arrays once per launch. .w gets the h=0 initial Atilde.
__global__ void pack_init(const float* __restrict__ x, const float* __restrict__ y,
                          float4* pkfab, float4* pkgab,
                          float4* pkfaa0, float4* pkfaa1,
                          float4* pkgbb0, float4* pkgbb1)
{
  int i = blockIdx.x*256 + threadIdx.x;        // 0..16383 == b*4096+m
  const float* xp = x + (size_t)i*3;
  float xx = xp[0], xy = xp[1], xz = xp[2];
  float4 vx; vx.x=xx; vx.y=xy; vx.z=xz;
  vx.w = -0.5f*(xx*xx + xy*xy + xz*xz)*KSCALE;
  const float* yp = y + (size_t)i*4;
  float yx = yp[0], yy = yp[1], yz = yp[2];
  float4 vy; vy.x=yx; vy.y=yy; vy.z=yz;
  vy.w = -0.5f*(yx*yx + yy*yy + yz*yz)*KSCALE;
  pkgab[i]  = vx; pkfaa0[i] = vx; pkfaa1[i] = vx;
  pkfab[i]  = vy; pkgbb0[i] = vy; pkgbb1[i] = vy;
}

__global__ void reduce_kernel(const float* __restrict__ fab, const float* __restrict__ faa,
                              const float* __restrict__ gab, const float* __restrict__ gbb,
                              float* __restrict__ out)
{
  int b = blockIdx.x;
  int tid = threadIdx.x;
  float s = 0.f;
  for (int i = tid; i < NPTS; i += 256) {
    int idx = b*NPTS + i;
    s += (fab[idx] - faa[idx]) + (gab[idx] - gbb[idx]);
  }
  for (int off = 32; off > 0; off >>= 1) s += __shfl_down(s, off, 64);
  __shared__ float red[4];
  if ((tid & 63) == 0) red[tid >> 6] = s;
  __syncthreads();
  if (tid == 0) out[b] = (red[0]+red[1]+red[2]+red[3]) * (1.0f/NPTS);
}

extern "C" void kernel_launch(void* const* d_in, const int* in_sizes, int n_in,
                              void* d_out, int out_size, void* d_ws, size_t ws_size,
                              hipStream_t stream)
{
  const float* x = (const float*)d_in[0];   // (4,4096,3)
  const float* y = (const float*)d_in[1];   // (4,4096,4), first 3 comps used
  float* ws = (float*)d_ws;
  const size_t P = (size_t)NBATCH * NPTS;   // 16384

  float* f_ab    = ws + 0*P;
  float* g_ab    = ws + 1*P;
  float* faaR[2] = { ws + 2*P, ws + 4*P };
  float* gbbR[2] = { ws + 3*P, ws + 5*P };
  float4* pk4    = (float4*)(ws + 6*P);
  float4* PKfab    = pk4 + 0*P;             // cols = y, .w = Atilde(g_ab)
  float4* PKgab    = pk4 + 1*P;             // cols = x, .w = Atilde(f_ab)
  float4* PKfaa[2] = { pk4 + 2*P, pk4 + 3*P };
  float4* PKgbb[2] = { pk4 + 4*P, pk4 + 5*P };

  // zero h_old for the first averaged symmetric step (faaR[0], gbbR[0] contiguous)
  hipMemsetAsync(ws + 2*P, 0, 2*P*sizeof(float), stream);
  pack_init<<<dim3(P/256), dim3(256), 0, stream>>>(x, y, PKfab, PKgab,
                                                   PKfaa[0], PKfaa[1], PKgbb[0], PKgbb[1]);

  for (int i = 0; i < 21; ++i) {
    int cur = i & 1, nxt = cur ^ 1;
    int modeS = (i < 20) ? 1 : 0;    // averaged symmetric update except final softmin
    // phase 1: f_ab = softmin over y-cols (Atilde from g_ab)  ||  f_aa step
    softmin_kernel<<<1024, BLOCK, 0, stream>>>(
        x, 3, PKfab, PKgab, f_ab, f_ab, 0,
        x, 3, PKfaa[cur], PKfaa[nxt], faaR[cur], faaR[nxt], modeS);
    // phase 2: g_ab = softmin over x-cols (Atilde from f_ab)  ||  g_bb step
    softmin_kernel<<<1024, BLOCK, 0, stream>>>(
        y, 4, PKgab, PKfab, g_ab, g_ab, 0,
        y, 4, PKgbb[cur], PKgbb[nxt], gbbR[cur], gbbR[nxt], modeS);
  }
  // i=20 wrote faaR[1]/gbbR[1]
  reduce_kernel<<<dim3(4), dim3(256), 0, stream>>>(f_ab, faaR[1], g_ab, gbbR[1], (float*)d_out);
}

// Round 9
// 1016.180 us; speedup vs baseline: 2.7711x; 1.2278x over previous
//
#include <hip/hip_runtime.h>
#include <math.h>

#define NPTS 4096
#define NBATCH 4
#define BLOCK 512        // 8 waves, 64 rows per block
#define RPW 8            // rows per wave (coords in SGPRs)

static constexpr float KSCALE     = 1.4426950408889634f / 1e-4f;   // log2(e)/eps
static constexpr float INVK2      = 1.0f / (KSCALE * KSCALE);
static constexpr float EPSLN2     = 1e-4f * 0.6931471805599453f;   // eps*ln(2)
static constexpr float NEGEPSLOGW = 8.31776616671934e-4f;          // -eps * (-log(4096))
static constexpr float THR        = 20.0f;   // drop chunks < mu-20: rel mass <= 4096*2^-20

__device__ __forceinline__ float fexp2(float x){
#if __has_builtin(__builtin_amdgcn_exp2f)
  return __builtin_amdgcn_exp2f(x);
#else
  return exp2f(x);
#endif
}
__device__ __forceinline__ float flog2(float x){
#if __has_builtin(__builtin_amdgcn_logf)
  return __builtin_amdgcn_logf(x);
#else
  return log2f(x);
#endif
}
__device__ __forceinline__ float frl(float x){
  return __int_as_float(__builtin_amdgcn_readfirstlane(__float_as_int(x)));
}

// Two-pass softmin, LDS-staged columns + chunk-max skip.
// One launch = two problems (256 blocks each). Block = 512 thr = 8 waves,
// 64 rows/block; wave owns 8 rows (coords in SGPRs). The 64 KB column pack
// is staged to LDS once per block (global traffic/CU: 2.1MB -> 128KB),
// then both passes read lane-distinct ds_read_b128 (2-way conflict = free).
// Pass A: dots + max3 -> cmax[4 chunks][8 rows] (32 VGPR; safe under the
// 128-reg budget of launch_bounds(512,4)); fold + shfl -> exact mu.
// Pass B: only chunks with __any(cmax > mu-THR) are re-dotted + exp2'd;
// wave-uniform chunk branch, per-row bit prune inside. No rescale path.
__global__ __launch_bounds__(BLOCK, 4) void softmin_kernel(
    const float* __restrict__ rowA, int rsA, const float4* __restrict__ pkInA,
    float4* __restrict__ pkOutA, const float* __restrict__ hOldA,
    float* __restrict__ outA, int modeA,
    const float* __restrict__ rowB, int rsB, const float4* __restrict__ pkInB,
    float4* __restrict__ pkOutB, const float* __restrict__ hOldB,
    float* __restrict__ outB, int modeB)
{
  __shared__ float4 qs[NPTS];          // 64 KB

  int bid = blockIdx.x;
  const float* rowp; const float4* pkin; float4* pkout; const float* hold;
  float* outp; int rs, mode;
  if (bid < 256) { rowp=rowA; pkin=pkInA; pkout=pkOutA; hold=hOldA; outp=outA; rs=rsA; mode=modeA; }
  else           { rowp=rowB; pkin=pkInB; pkout=pkOutB; hold=hOldB; outp=outB; rs=rsB; mode=modeB; }
  int lb = bid & 255;
  int b  = lb >> 6;          // batch (64 blocks per batch)
  int rb = lb & 63;          // row-block (64 rows per block)

  int tid = threadIdx.x;
  int lane = tid & 63;
  int wu = __builtin_amdgcn_readfirstlane(tid >> 6);
  int r0 = rb*64 + wu*RPW;
  int ridx0 = b*NPTS + r0;

  // ---- stage the whole column pack into LDS (once) ----
  {
    const float4* src = pkin + b*NPTS;
    #pragma unroll
    for (int i = 0; i < NPTS/BLOCK; ++i)
      qs[i*BLOCK + tid] = src[i*BLOCK + tid];
  }

  // wave-uniform row coords -> SGPRs (overlaps staging latency)
  float sx[RPW], sy[RPW], sz[RPW];
  #pragma unroll
  for (int i = 0; i < RPW; ++i) {
    const float* p = rowp + (size_t)(ridx0 + i) * rs;
    sx[i] = frl(p[0]*KSCALE); sy[i] = frl(p[1]*KSCALE); sz[i] = frl(p[2]*KSCALE);
  }

  __syncthreads();

  // ---- pass A: dots + max3 -> cmax[4][8] ----
  float cmax[4][RPW];
  #pragma unroll
  for (int c = 0; c < 4; ++c)
    #pragma unroll
    for (int r = 0; r < RPW; ++r) cmax[c][r] = -INFINITY;

  #pragma unroll
  for (int c = 0; c < 4; ++c) {
    #pragma unroll
    for (int g = 0; g < 4; ++g) {
      int base = c*1024 + g*256 + lane;
      float4 q0 = qs[base], q1 = qs[base+64], q2 = qs[base+128], q3 = qs[base+192];
      #pragma unroll
      for (int r = 0; r < RPW; ++r) {
        float t0 = fmaf(sx[r],q0.x,fmaf(sy[r],q0.y,fmaf(sz[r],q0.z,q0.w)));
        float t1 = fmaf(sx[r],q1.x,fmaf(sy[r],q1.y,fmaf(sz[r],q1.z,q1.w)));
        float t2 = fmaf(sx[r],q2.x,fmaf(sy[r],q2.y,fmaf(sz[r],q2.z,q2.w)));
        float t3 = fmaf(sx[r],q3.x,fmaf(sy[r],q3.y,fmaf(sz[r],q3.z,q3.w)));
        float u  = fmaxf(fmaxf(t0,t1),t2);        // v_max3
        cmax[c][r] = fmaxf(fmaxf(u,t3),cmax[c][r]); // v_max3
      }
    }
  }

  // exact global max per row
  float M[RPW];
  #pragma unroll
  for (int r = 0; r < RPW; ++r) {
    float mm = fmaxf(fmaxf(cmax[0][r],cmax[1][r]), fmaxf(cmax[2][r],cmax[3][r]));
    #pragma unroll
    for (int off = 32; off; off >>= 1) mm = fmaxf(mm, __shfl_xor(mm, off, 64));
    M[r] = mm;
  }

  // ---- pass B: exp2 over active chunks only ----
  float S[RPW];
  #pragma unroll
  for (int r = 0; r < RPW; ++r) S[r] = 0.f;

  #pragma unroll
  for (int c = 0; c < 4; ++c) {
    int am = 0;
    #pragma unroll
    for (int r = 0; r < RPW; ++r)
      am |= __any(cmax[c][r] > M[r] - THR) ? (1 << r) : 0;
    if (am) {
      #pragma unroll
      for (int g = 0; g < 4; ++g) {
        int base = c*1024 + g*256 + lane;
        float4 q0 = qs[base], q1 = qs[base+64], q2 = qs[base+128], q3 = qs[base+192];
        #pragma unroll
        for (int r = 0; r < RPW; ++r) if (am & (1 << r)) {
          float t0 = fmaf(sx[r],q0.x,fmaf(sy[r],q0.y,fmaf(sz[r],q0.z,q0.w)));
          float t1 = fmaf(sx[r],q1.x,fmaf(sy[r],q1.y,fmaf(sz[r],q1.z,q1.w)));
          float t2 = fmaf(sx[r],q2.x,fmaf(sy[r],q2.y,fmaf(sz[r],q2.z,q2.w)));
          float t3 = fmaf(sx[r],q3.x,fmaf(sy[r],q3.y,fmaf(sz[r],q3.z,q3.w)));
          float e0 = fexp2(t0-M[r]) + fexp2(t1-M[r]);
          float e1 = fexp2(t2-M[r]) + fexp2(t3-M[r]);
          S[r] += e0 + e1;
        }
      }
    }
  }

  // ---- merge + write ----
  #pragma unroll
  for (int r = 0; r < RPW; ++r) {
    float s = S[r];
    #pragma unroll
    for (int off = 32; off; off >>= 1) s += __shfl_xor(s, off, 64);
    float ch = 0.5f*(sx[r]*sx[r] + sy[r]*sy[r] + sz[r]*sz[r]) * INVK2;
    float res = fmaf(-EPSLN2, M[r] + flog2(s), ch + NEGEPSLOGW);
    if (lane == r) {
      if (mode) res = 0.5f*(hold[ridx0 + r] + res);
      outp[ridx0 + r] = res;
      ((float*)(pkout + (ridx0 + r)))[3] = (res - ch) * KSCALE;
    }
  }
}

// Build the 6 packed column arrays once per launch. .w gets the h=0 initial Atilde.
__global__ void pack_init(const float* __restrict__ x, const float* __restrict__ y,
                          float4* pkfab, float4* pkgab,
                          float4* pkfaa0, float4* pkfaa1,
                          float4* pkgbb0, float4* pkgbb1)
{
  int i = blockIdx.x*256 + threadIdx.x;        // 0..16383 == b*4096+m
  const float* xp = x + (size_t)i*3;
  float xx = xp[0], xy = xp[1], xz = xp[2];
  float4 vx; vx.x=xx; vx.y=xy; vx.z=xz;
  vx.w = -0.5f*(xx*xx + xy*xy + xz*xz)*KSCALE;
  const float* yp = y + (size_t)i*4;
  float yx = yp[0], yy = yp[1], yz = yp[2];
  float4 vy; vy.x=yx; vy.y=yy; vy.z=yz;
  vy.w = -0.5f*(yx*yx + yy*yy + yz*yz)*KSCALE;
  pkgab[i]  = vx; pkfaa0[i] = vx; pkfaa1[i] = vx;
  pkfab[i]  = vy; pkgbb0[i] = vy; pkgbb1[i] = vy;
}

__global__ void reduce_kernel(const float* __restrict__ fab, const float* __restrict__ faa,
                              const float* __restrict__ gab, const float* __restrict__ gbb,
                              float* __restrict__ out)
{
  int b = blockIdx.x;
  int tid = threadIdx.x;
  float s = 0.f;
  for (int i = tid; i < NPTS; i += 256) {
    int idx = b*NPTS + i;
    s += (fab[idx] - faa[idx]) + (gab[idx] - gbb[idx]);
  }
  for (int off = 32; off > 0; off >>= 1) s += __shfl_down(s, off, 64);
  __shared__ float red[4];
  if ((tid & 63) == 0) red[tid >> 6] = s;
  __syncthreads();
  if (tid == 0) out[b] = (red[0]+red[1]+red[2]+red[3]) * (1.0f/NPTS);
}

extern "C" void kernel_launch(void* const* d_in, const int* in_sizes, int n_in,
                              void* d_out, int out_size, void* d_ws, size_t ws_size,
                              hipStream_t stream)
{
  const float* x = (const float*)d_in[0];   // (4,4096,3)
  const float* y = (const float*)d_in[1];   // (4,4096,4), first 3 comps used
  float* ws = (float*)d_ws;
  const size_t P = (size_t)NBATCH * NPTS;   // 16384

  float* f_ab    = ws + 0*P;
  float* g_ab    = ws + 1*P;
  float* faaR[2] = { ws + 2*P, ws + 4*P };
  float* gbbR[2] = { ws + 3*P, ws + 5*P };
  float4* pk4    = (float4*)(ws + 6*P);
  float4* PKfab    = pk4 + 0*P;             // cols = y, .w = Atilde(g_ab)
  float4* PKgab    = pk4 + 1*P;             // cols = x, .w = Atilde(f_ab)
  float4* PKfaa[2] = { pk4 + 2*P, pk4 + 3*P };
  float4* PKgbb[2] = { pk4 + 4*P, pk4 + 5*P };

  // zero h_old for the first averaged symmetric step (faaR[0], gbbR[0] contiguous)
  hipMemsetAsync(ws + 2*P, 0, 2*P*sizeof(float), stream);
  pack_init<<<dim3(P/256), dim3(256), 0, stream>>>(x, y, PKfab, PKgab,
                                                   PKfaa[0], PKfaa[1], PKgbb[0], PKgbb[1]);

  for (int i = 0; i < 21; ++i) {
    int cur = i & 1, nxt = cur ^ 1;
    int modeS = (i < 20) ? 1 : 0;    // averaged symmetric update except final softmin
    // phase 1: f_ab = softmin over y-cols (Atilde from g_ab)  ||  f_aa step
    softmin_kernel<<<512, BLOCK, 0, stream>>>(
        x, 3, PKfab, PKgab, f_ab, f_ab, 0,
        x, 3, PKfaa[cur], PKfaa[nxt], faaR[cur], faaR[nxt], modeS);
    // phase 2: g_ab = softmin over x-cols (Atilde from f_ab)  ||  g_bb step
    softmin_kernel<<<512, BLOCK, 0, stream>>>(
        y, 4, PKgab, PKfab, g_ab, g_ab, 0,
        y, 4, PKgbb[cur], PKgbb[nxt], gbbR[cur], gbbR[nxt], modeS);
  }
  // i=20 wrote faaR[1]/gbbR[1]
  reduce_kernel<<<dim3(4), dim3(256), 0, stream>>>(f_ab, faaR[1], g_ab, gbbR[1], (float*)d_out);
}